// Round 4
// baseline (186.005 us; speedup 1.0000x reference)
//
#include <hip/hip_runtime.h>
#include <hip/hip_bf16.h>
#include <math.h>

#define D 1024
#define H 16
#define DH 64
#define L 2048
#define B 2
#define NROW (B * L)  // 4096
#define EPS 1e-5f

typedef _Float16 half8 __attribute__((ext_vector_type(8)));
typedef _Float16 half4v __attribute__((ext_vector_type(4)));
typedef float f32x4 __attribute__((ext_vector_type(4)));

// ---------------------------------------------------------------------------
// K1: prep kernel — fuses 4 independent preprocessing jobs, block-ranged:
//  [0,4096)      LN1 (stats+apply) -> h16
//  [4096,6144)   f32->f16 weight convert (w_qkv then out_w)
//  [6144,6160)   segment bounds from sorted seq_id
//  [6160,6416)   rope cos/sin table [L][32] (float2)
// ---------------------------------------------------------------------------
__global__ __launch_bounds__(256) void prep_kernel(const float* __restrict__ x,
                                                   const float* __restrict__ lw,
                                                   const float* __restrict__ lb,
                                                   _Float16* __restrict__ h16,
                                                   const float* __restrict__ wqkv,
                                                   _Float16* __restrict__ wqkv16,
                                                   const float* __restrict__ outw,
                                                   _Float16* __restrict__ outw16,
                                                   const int* __restrict__ seq_id,
                                                   int* __restrict__ lo,
                                                   int* __restrict__ hi,
                                                   float2* __restrict__ rtab) {
    int blk = blockIdx.x;
    int t = threadIdx.x;
    if (blk < 4096) {
        // ---- LN1 row ----
        int r = blk;
        const float* xr = x + (size_t)r * D;
        float4 v = *(const float4*)&xr[t * 4];
        float s = v.x + v.y + v.z + v.w;
        float sq = v.x * v.x + v.y * v.y + v.z * v.z + v.w * v.w;
        for (int off = 32; off > 0; off >>= 1) {
            s += __shfl_xor(s, off, 64);
            sq += __shfl_xor(sq, off, 64);
        }
        __shared__ float ls[4], lq[4];
        int wave = t >> 6;
        if ((t & 63) == 0) { ls[wave] = s; lq[wave] = sq; }
        __syncthreads();
        float S = ls[0] + ls[1] + ls[2] + ls[3];
        float Q = lq[0] + lq[1] + lq[2] + lq[3];
        float mu = S / (float)D;
        float rs = rsqrtf(Q / (float)D - mu * mu + EPS);
        float4 w4 = *(const float4*)&lw[t * 4];
        float4 b4 = *(const float4*)&lb[t * 4];
        half4v o = {(_Float16)((v.x - mu) * rs * w4.x + b4.x),
                    (_Float16)((v.y - mu) * rs * w4.y + b4.y),
                    (_Float16)((v.z - mu) * rs * w4.z + b4.z),
                    (_Float16)((v.w - mu) * rs * w4.w + b4.w)};
        *(half4v*)&h16[(size_t)r * D + t * 4] = o;
    } else if (blk < 6144) {
        // ---- weight convert ----
        int base = blk - 4096;
        const float* src;
        _Float16* dst;
        if (base < 1536) { src = wqkv; dst = wqkv16; }
        else             { src = outw; dst = outw16; base -= 1536; }
        int i = (base * 256 + t) * 8;
        float4 a = *(const float4*)&src[i];
        float4 b = *(const float4*)&src[i + 4];
        half8 h = {(_Float16)a.x, (_Float16)a.y, (_Float16)a.z, (_Float16)a.w,
                   (_Float16)b.x, (_Float16)b.y, (_Float16)b.z, (_Float16)b.w};
        *(half8*)&dst[i] = h;
    } else if (blk < 6160) {
        // ---- segment bounds ----
        int idx = (blk - 6144) * 256 + t;
        int b = idx / L, l = idx - b * L;
        const int* row = seq_id + (size_t)b * L;
        int v = row[l];
        int a = 0, c = L;
        while (a < c) { int m = (a + c) >> 1; if (row[m] < v) a = m + 1; else c = m; }
        lo[idx] = a;
        a = 0; c = L;
        while (a < c) { int m = (a + c) >> 1; if (row[m] <= v) a = m + 1; else c = m; }
        hi[idx] = a;
    } else {
        // ---- rope table: rtab[l*32+fi] = (cos, sin) of l * 10000^(-fi/32) ----
        int idx = (blk - 6160) * 256 + t;  // 0..65535
        int l = idx >> 5, fi = idx & 31;
        float invf = expf(-(float)fi * 0.28782313662425572f);  // ln(10000)/32
        float sn, cs;
        sincosf((float)l * invf, &sn, &cs);
        rtab[idx] = make_float2(cs, sn);
    }
}

// ---------------------------------------------------------------------------
// K2: f16 MFMA GEMM  C[M,N] = A[M,1024] * W[N,1024]^T
// BM x BN tile, BK=32, 4 waves in 2x2. Single-barrier double-buffered K-loop.
// (Counted-vmcnt / 8-phase grafts on this structure are measured-neutral —
// m131/m139 and our round-2 A/B — so the 2-barrier loop stays.)
// XOR source-swizzle keeps fragment ds_read_b128 conflict-free (2-way).
// Bijective linear XCD chunk swizzle (nwg % 8 == 0 required).
//
// VSPLIT: head-aligned N-blocks with n0 >= 2048 are pure-V columns of the
// qkv projection. Their epilogue writes the TRANSPOSED v_t[bh][d][l] layout
// directly (4 consecutive l per lane -> packed b64 stores), skipping the
// qkv16 write AND the whole mid-kernel V-transpose pass (24 MB intermediate
// traffic). Bit-identical numerics: same MFMA acc, same single f16 round.
// ---------------------------------------------------------------------------
template <typename OutT, int BM, int BN, bool VSPLIT>
__global__ __launch_bounds__(256) void gemm_f16_kernel(const _Float16* __restrict__ A,
                                                       const _Float16* __restrict__ W,
                                                       OutT* __restrict__ C, int N,
                                                       _Float16* __restrict__ v_t) {
    constexpr int WM = BM / 2, WN = BN / 2;
    constexpr int MT = WM / 16, NT = WN / 16;
    __shared__ _Float16 As[2][BM * 32];
    __shared__ _Float16 Bs[2][BN * 32];
    int t = threadIdx.x;
    int w = t >> 6, lane = t & 63;
    int quad = lane >> 4, col = lane & 15;
    int nx = gridDim.x;
    int ib = blockIdx.y * nx + blockIdx.x;
    int nwg = nx * gridDim.y;
    int ni = (ib & 7) * (nwg >> 3) + (ib >> 3);
    int m0 = (ni / nx) * BM, n0 = (ni % nx) * BN;
    int mw = (w >> 1) * WM, nw = (w & 1) * WN;
    int sw = (col >> 1) & 3;  // fragment-read swizzle == (row>>1)&3 for row=…+col

    f32x4 acc[MT][NT] = {};

    auto stage = [&](int k0, int buf) {
#pragma unroll
        for (int i = 0; i < BM / 64; i++) {
            int e = t + i * 256;
            int row = e >> 2, kc = (e & 3) ^ ((row >> 1) & 3);
            __builtin_amdgcn_global_load_lds(
                (const __attribute__((address_space(1))) void*)&A[(size_t)(m0 + row) * 1024 + k0 + kc * 8],
                (__attribute__((address_space(3))) void*)&As[buf][e * 8], 16, 0, 0);
        }
#pragma unroll
        for (int i = 0; i < BN / 64; i++) {
            int e = t + i * 256;
            int row = e >> 2, kc = (e & 3) ^ ((row >> 1) & 3);
            __builtin_amdgcn_global_load_lds(
                (const __attribute__((address_space(1))) void*)&W[(size_t)(n0 + row) * 1024 + k0 + kc * 8],
                (__attribute__((address_space(3))) void*)&Bs[buf][e * 8], 16, 0, 0);
        }
    };

    stage(0, 0);
    int cur = 0;
    for (int k0 = 0; k0 < 1024; k0 += 32) {
        __syncthreads();
        if (k0 + 32 < 1024) stage(k0 + 32, cur ^ 1);
        half8 af[MT], bf[NT];
#pragma unroll
        for (int mt = 0; mt < MT; mt++)
            af[mt] = *(const half8*)&As[cur][(mw + mt * 16 + col) * 32 + ((quad ^ sw) << 3)];
#pragma unroll
        for (int nt = 0; nt < NT; nt++)
            bf[nt] = *(const half8*)&Bs[cur][(nw + nt * 16 + col) * 32 + ((quad ^ sw) << 3)];
#pragma unroll
        for (int mt = 0; mt < MT; mt++)
#pragma unroll
            for (int nt = 0; nt < NT; nt++)
                acc[mt][nt] = __builtin_amdgcn_mfma_f32_16x16x32_f16(af[mt], bf[nt], acc[mt][nt], 0, 0, 0);
        cur ^= 1;
    }

    if (VSPLIT && n0 >= 2048) {
        // V block: write transposed into v_t[bh][d][l]. All rows of this
        // block share one batch b (2048 % BM == 0). l-packing: quad*4 + r
        // are 4 consecutive l -> one b64 store per (mt,nt).
        int b = m0 >> 11;
#pragma unroll
        for (int mt = 0; mt < MT; mt++)
#pragma unroll
            for (int nt = 0; nt < NT; nt++) {
                int vcol = n0 - 2048 + nw + nt * 16 + col;  // h*64 + d
                int bh = b * H + (vcol >> 6);
                int d = vcol & 63;
                int l = (m0 & (L - 1)) + mw + mt * 16 + quad * 4;
                half4v pk = {(_Float16)acc[mt][nt][0], (_Float16)acc[mt][nt][1],
                             (_Float16)acc[mt][nt][2], (_Float16)acc[mt][nt][3]};
                *(half4v*)&v_t[((size_t)(bh * 64 + d)) * 2048 + l] = pk;
            }
    } else {
#pragma unroll
        for (int mt = 0; mt < MT; mt++)
#pragma unroll
            for (int nt = 0; nt < NT; nt++)
#pragma unroll
                for (int r = 0; r < 4; r++) {
                    int row = m0 + mw + mt * 16 + quad * 4 + r;
                    int cc = n0 + nw + nt * 16 + col;
                    C[(size_t)row * N + cc] = (OutT)acc[mt][nt][r];
                }
    }
}

// ---------------------------------------------------------------------------
// K3: mid kernel — Q/K LayerNorm + RoPE -> f16 q_r/k_r, one block per row,
// 16B half8 loads/stores. Thread t<128 owns q elems 8t..8t+7; t>=128 same
// for k. RoPE partner j^32 == lane^4. (V-transpose now fused into gemm1's
// epilogue — this kernel no longer touches V.)
// ---------------------------------------------------------------------------
__global__ __launch_bounds__(256) void mid_kernel(const _Float16* __restrict__ qkv,
                                                  const float* __restrict__ qw,
                                                  const float* __restrict__ kw,
                                                  const float2* __restrict__ rtab,
                                                  _Float16* __restrict__ q_r,
                                                  _Float16* __restrict__ k_r) {
    __shared__ float ls[4], lq[4];
    int t = threadIdx.x;
    int r = blockIdx.x;
    int half = t >> 7;      // 0 = q, 1 = k (wave-uniform)
    int tt = t & 127;
    const _Float16* src = qkv + (size_t)r * 3072 + half * 1024;
    const float* wgt = half ? kw : qw;
    _Float16* dst = half ? k_r : q_r;

    half8 hv = *(const half8*)&src[tt * 8];
    float y[8];
    float s = 0.f, sq = 0.f;
#pragma unroll
    for (int e = 0; e < 8; e++) {
        float v = (float)hv[e];
        y[e] = v;
        s += v;
        sq += v * v;
    }
    for (int off = 32; off > 0; off >>= 1) {
        s += __shfl_xor(s, off, 64);
        sq += __shfl_xor(sq, off, 64);
    }
    int wave = t >> 6;
    if ((t & 63) == 0) { ls[wave] = s; lq[wave] = sq; }
    __syncthreads();
    int base = half << 1;
    float S = ls[base] + ls[base + 1];
    float Q = lq[base] + lq[base + 1];
    float mu = S / 1024.f;
    float rs = rsqrtf(Q / 1024.f - mu * mu + EPS);

    int l = r & (L - 1);
    int b = r >> 11;
    int j0 = tt * 8;
    int dh0 = j0 & 63, hh = j0 >> 6;
    const float2* cp = &rtab[l * 32 + (dh0 & 31)];
    float4 c01 = *(const float4*)cp;          // (cos,sin) pairs e=0,1
    float4 c23 = *(const float4*)(cp + 2);
    float4 c45 = *(const float4*)(cp + 4);
    float4 c67 = *(const float4*)(cp + 6);
    float cs_[8] = {c01.x, c01.z, c23.x, c23.z, c45.x, c45.z, c67.x, c67.z};
    float sn_[8] = {c01.y, c01.w, c23.y, c23.w, c45.y, c45.w, c67.y, c67.w};

    float yn[8];
#pragma unroll
    for (int e = 0; e < 8; e++) yn[e] = (y[e] - mu) * rs * wgt[j0 + e];
    float sgn = (dh0 < 32) ? -1.f : 1.f;
    half8 o;
#pragma unroll
    for (int e = 0; e < 8; e++) {
        float p = __shfl_xor(yn[e], 4, 64);   // partner element j^32
        o[e] = (_Float16)(yn[e] * cs_[e] + sgn * p * sn_[e]);
    }
    *(half8*)&dst[((size_t)((b * H + hh) * L + l)) * 64 + dh0] = o;
}

// ---------------------------------------------------------------------------
// K4: MFMA flash attention, segment-pruned, swapped-operand layout.
// QBLK=128 (8 waves), KV tile 64, double-buffered global_load_lds staging
// with pre-swizzled global source. mfma(K,Q) puts a full P-row in-lane
// (query = col); softmax = 15 in-lane ops + 2 shfl; P via 4 packed b64
// writes to XOR-swizzled wave-private Ps. LDS 48KB.
// ---------------------------------------------------------------------------
__global__ __launch_bounds__(512) void attn_mfma_kernel(const _Float16* __restrict__ q_r,
                                                        const _Float16* __restrict__ k_r,
                                                        const _Float16* __restrict__ v_t,
                                                        const int* __restrict__ lo_arr,
                                                        const int* __restrict__ hi_arr,
                                                        _Float16* __restrict__ ctx) {
    __shared__ _Float16 Ks[2][64][64];
    __shared__ _Float16 Vs[2][64][64];
    __shared__ _Float16 Ps[8][16][64];
    int bh = blockIdx.y;
    int b = bh >> 4, h = bh & 15;
    int l0 = blockIdx.x * 128;
    int t = threadIdx.x;
    int w = t >> 6, lane = t & 63;
    int quad = lane >> 4, col = lane & 15;
    int rbase = l0 + w * 16;

    int blo = lo_arr[b * L + l0] & ~63;
    int bhi = hi_arr[b * L + l0 + 127];

    auto stage = [&](int m0, int buf) {
        int row = t >> 3, ch = t & 7;          // 512 threads = 64 rows x 8 chunks
        int sch = ch ^ (row & 7);              // pre-swizzled global source (m173)
        __builtin_amdgcn_global_load_lds(
            (const __attribute__((address_space(1))) void*)&k_r[((size_t)(bh * L + m0 + row)) * 64 + sch * 8],
            (__attribute__((address_space(3))) void*)&Ks[buf][row][ch * 8], 16, 0, 0);
        __builtin_amdgcn_global_load_lds(
            (const __attribute__((address_space(1))) void*)&v_t[((size_t)(bh * 64 + row)) * 2048 + m0 + sch * 8],
            (__attribute__((address_space(3))) void*)&Vs[buf][row][ch * 8], 16, 0, 0);
    };

    stage(blo, 0);

    // Q fragment (B-operand): B[col=query][k = quad*8..], query = rbase+col
    half8 qf0, qf1;
    {
        const _Float16* qp = q_r + ((size_t)(bh * L + rbase + col)) * 64 + quad * 8;
        qf0 = *(const half8*)qp;
        qf1 = *(const half8*)(qp + 32);
    }
    int lo_c = lo_arr[b * L + rbase + col];  // per-lane query bounds
    int hi_c = hi_arr[b * L + rbase + col];
    int wlo = __shfl(lo_c, 15, 64);  // max lo over wave's queries (monotone)
    int whi = __shfl(hi_c, 0, 64);   // min hi over wave's queries

    f32x4 o[4] = {};
    float m_run = -1e30f, l_run = 0.f;
    const float SCL = 0.125f * 1.4426950408889634f;  // (1/sqrt(DH)) * log2(e)
    int swz = (col & 7) << 3;
    int src = (lane & 48) | ((lane & 48) >> 2);  // lane holding corr for row quad*4+r

    int cur = 0;
    for (int m0 = blo; m0 < bhi; m0 += 64) {
        __syncthreads();  // implicit vmcnt(0): buf[cur] staged by all waves
        if (m0 + 64 < bhi) stage(m0 + 64, cur ^ 1);

        // QK^T swapped: s[nt] row = key (nt*16 + quad*4 + r), col = query
        f32x4 s[4] = {};
#pragma unroll
        for (int nt = 0; nt < 4; nt++) {
            int key = nt * 16 + col;
            const _Float16* kp = &Ks[cur][key][0];
            half8 kf0 = *(const half8*)&kp[(quad ^ (key & 7)) * 8];
            half8 kf1 = *(const half8*)&kp[((quad + 4) ^ (key & 7)) * 8];
            s[nt] = __builtin_amdgcn_mfma_f32_16x16x32_f16(kf0, qf0, s[nt], 0, 0, 0);
            s[nt] = __builtin_amdgcn_mfma_f32_16x16x32_f16(kf1, qf1, s[nt], 0, 0, 0);
        }

        float p[4][4];
        bool full = (m0 >= wlo) && (m0 + 64 <= whi);  // wave-uniform branch
        if (full) {
#pragma unroll
            for (int nt = 0; nt < 4; nt++)
#pragma unroll
                for (int r = 0; r < 4; r++) p[nt][r] = s[nt][r] * SCL;
        } else {
#pragma unroll
            for (int nt = 0; nt < 4; nt++) {
                int kb = m0 + nt * 16 + quad * 4;
#pragma unroll
                for (int r = 0; r < 4; r++) {
                    int key = kb + r;
                    p[nt][r] = (key >= lo_c && key < hi_c) ? s[nt][r] * SCL : -INFINITY;
                }
            }
        }

        // online softmax for this lane's query (col): 15 in-lane + 2 shfl
        float tmax = p[0][0];
#pragma unroll
        for (int nt = 0; nt < 4; nt++)
#pragma unroll
            for (int r = 0; r < 4; r++) tmax = fmaxf(tmax, p[nt][r]);
        tmax = fmaxf(tmax, __shfl_xor(tmax, 16, 64));
        tmax = fmaxf(tmax, __shfl_xor(tmax, 32, 64));
        float nm = fmaxf(m_run, tmax);
        float corr = exp2f(m_run - nm);
        m_run = nm;
        float rs = 0.f;
#pragma unroll
        for (int nt = 0; nt < 4; nt++)
#pragma unroll
            for (int r = 0; r < 4; r++) {
                float e2 = exp2f(p[nt][r] - nm);
                p[nt][r] = e2;
                rs += e2;
            }
        rs += __shfl_xor(rs, 16, 64);
        rs += __shfl_xor(rs, 32, 64);
        l_run = l_run * corr + rs;

        // P -> LDS: 4 packed b64 writes, Ps[w][query][key ^ swz(query)]
#pragma unroll
        for (int nt = 0; nt < 4; nt++) {
            half4v pk = {(_Float16)p[nt][0], (_Float16)p[nt][1],
                         (_Float16)p[nt][2], (_Float16)p[nt][3]};
            *(half4v*)&Ps[w][col][(nt * 16 + quad * 4) ^ swz] = pk;
        }

        // O-rescale: corr lives at lanes with col==query; PV rows are quad*4+r
#pragma unroll
        for (int r = 0; r < 4; r++) {
            float c4 = __shfl(corr, src + r, 64);
            o[0][r] *= c4; o[1][r] *= c4; o[2][r] *= c4; o[3][r] *= c4;
        }

        // PV: A = P[query][key], B = V^T[d][key]
        half8 pf0 = *(const half8*)&Ps[w][col][(quad * 8) ^ swz];
        half8 pf1 = *(const half8*)&Ps[w][col][(32 + quad * 8) ^ swz];
#pragma unroll
        for (int nt = 0; nt < 4; nt++) {
            int dr = nt * 16 + col;
            const _Float16* vp = &Vs[cur][dr][0];
            half8 vf0 = *(const half8*)&vp[(quad ^ (dr & 7)) * 8];
            half8 vf1 = *(const half8*)&vp[((quad + 4) ^ (dr & 7)) * 8];
            o[nt] = __builtin_amdgcn_mfma_f32_16x16x32_f16(pf0, vf0, o[nt], 0, 0, 0);
            o[nt] = __builtin_amdgcn_mfma_f32_16x16x32_f16(pf1, vf1, o[nt], 0, 0, 0);
        }
        cur ^= 1;
    }

#pragma unroll
    for (int r = 0; r < 4; r++) {
        float linv = 1.f / __shfl(l_run, src + r, 64);
        int row = rbase + quad * 4 + r;
#pragma unroll
        for (int nt = 0; nt < 4; nt++)
            ctx[((size_t)(b * L + row)) * 1024 + h * 64 + nt * 16 + col] =
                (_Float16)(o[nt][r] * linv);
    }
}

// ---------------------------------------------------------------------------
// launch
// ---------------------------------------------------------------------------
extern "C" void kernel_launch(void* const* d_in, const int* in_sizes, int n_in,
                              void* d_out, int out_size, void* d_ws, size_t ws_size,
                              hipStream_t stream) {
    const float* x      = (const float*)d_in[0];
    const int*   seq_id = (const int*)d_in[1];
    const float* ln1_w  = (const float*)d_in[2];
    const float* ln1_b  = (const float*)d_in[3];
    const float* w_qkv  = (const float*)d_in[4];
    const float* q_ln_w = (const float*)d_in[5];
    const float* k_ln_w = (const float*)d_in[6];
    const float* out_w  = (const float*)d_in[7];
    float* out = (float*)d_out;

    char* ws = (char*)d_ws;
    int*      lo     = (int*)(ws);                        // 16 KB
    int*      hi     = (int*)(ws + (64 << 10));           // 16 KB
    float2*   rtab   = (float2*)(ws + (128 << 10));       // [2048][32] f32x2, 512 KB
    _Float16* h16    = (_Float16*)(ws + (1ull << 20));    // [4096,1024] 8 MB
    _Float16* wqkv16 = (_Float16*)(ws + (10ull << 20));   // [3072,1024] 6 MB
    _Float16* outw16 = (_Float16*)(ws + (17ull << 20));   // [1024,1024] 2 MB
    _Float16* qkv16  = (_Float16*)(ws + (20ull << 20));   // [4096,3072] 24 MB (V third unused)
    _Float16* q_r    = (_Float16*)(ws + (45ull << 20));   // [B,H,L,DH] 8 MB
    _Float16* k_r    = (_Float16*)(ws + (54ull << 20));   // 8 MB
    _Float16* v_t    = (_Float16*)(ws + (63ull << 20));   // [B,H,DH,L] 8 MB
    _Float16* ctx16  = (_Float16*)(ws + (72ull << 20));   // [4096,1024] 8 MB

    prep_kernel<<<dim3(6416), dim3(256), 0, stream>>>(
        x, ln1_w, ln1_b, h16, w_qkv, wqkv16, out_w, outw16, seq_id, lo, hi, rtab);
    gemm_f16_kernel<_Float16, 128, 128, true><<<dim3(3072 / 128, NROW / 128), dim3(256), 0, stream>>>(
        h16, wqkv16, qkv16, 3072, v_t);
    mid_kernel<<<dim3(4096), dim3(256), 0, stream>>>(qkv16, q_ln_w, k_ln_w, rtab, q_r, k_r);
    attn_mfma_kernel<<<dim3(L / 128, B * H), dim3(512), 0, stream>>>(q_r, k_r, v_t, lo, hi, ctx16);
    gemm_f16_kernel<float, 128, 64, false><<<dim3(1024 / 64, NROW / 128), dim3(256), 0, stream>>>(
        ctx16, outw16, out, 1024, nullptr);

    (void)in_sizes; (void)n_in; (void)out_size; (void)ws_size;
}

// Round 5
// 184.492 us; speedup vs baseline: 1.0082x; 1.0082x over previous
//
#include <hip/hip_runtime.h>
#include <hip/hip_bf16.h>
#include <math.h>

#define D 1024
#define H 16
#define DH 64
#define L 2048
#define B 2
#define NROW (B * L)  // 4096
#define EPS 1e-5f

typedef _Float16 half8 __attribute__((ext_vector_type(8)));
typedef _Float16 half4v __attribute__((ext_vector_type(4)));
typedef float f32x4 __attribute__((ext_vector_type(4)));

// ---------------------------------------------------------------------------
// K1: prep kernel — fuses 4 independent preprocessing jobs, block-ranged:
//  [0,4096)      LN1 (stats+apply) -> h16
//  [4096,6144)   f32->f16 weight convert (w_qkv then out_w)
//  [6144,6160)   segment bounds from sorted seq_id
//  [6160,6416)   rope cos/sin table [L][32] (float2)
// ---------------------------------------------------------------------------
__global__ __launch_bounds__(256) void prep_kernel(const float* __restrict__ x,
                                                   const float* __restrict__ lw,
                                                   const float* __restrict__ lb,
                                                   _Float16* __restrict__ h16,
                                                   const float* __restrict__ wqkv,
                                                   _Float16* __restrict__ wqkv16,
                                                   const float* __restrict__ outw,
                                                   _Float16* __restrict__ outw16,
                                                   const int* __restrict__ seq_id,
                                                   int* __restrict__ lo,
                                                   int* __restrict__ hi,
                                                   float2* __restrict__ rtab) {
    int blk = blockIdx.x;
    int t = threadIdx.x;
    if (blk < 4096) {
        // ---- LN1 row ----
        int r = blk;
        const float* xr = x + (size_t)r * D;
        float4 v = *(const float4*)&xr[t * 4];
        float s = v.x + v.y + v.z + v.w;
        float sq = v.x * v.x + v.y * v.y + v.z * v.z + v.w * v.w;
        for (int off = 32; off > 0; off >>= 1) {
            s += __shfl_xor(s, off, 64);
            sq += __shfl_xor(sq, off, 64);
        }
        __shared__ float ls[4], lq[4];
        int wave = t >> 6;
        if ((t & 63) == 0) { ls[wave] = s; lq[wave] = sq; }
        __syncthreads();
        float S = ls[0] + ls[1] + ls[2] + ls[3];
        float Q = lq[0] + lq[1] + lq[2] + lq[3];
        float mu = S / (float)D;
        float rs = rsqrtf(Q / (float)D - mu * mu + EPS);
        float4 w4 = *(const float4*)&lw[t * 4];
        float4 b4 = *(const float4*)&lb[t * 4];
        half4v o = {(_Float16)((v.x - mu) * rs * w4.x + b4.x),
                    (_Float16)((v.y - mu) * rs * w4.y + b4.y),
                    (_Float16)((v.z - mu) * rs * w4.z + b4.z),
                    (_Float16)((v.w - mu) * rs * w4.w + b4.w)};
        *(half4v*)&h16[(size_t)r * D + t * 4] = o;
    } else if (blk < 6144) {
        // ---- weight convert ----
        int base = blk - 4096;
        const float* src;
        _Float16* dst;
        if (base < 1536) { src = wqkv; dst = wqkv16; }
        else             { src = outw; dst = outw16; base -= 1536; }
        int i = (base * 256 + t) * 8;
        float4 a = *(const float4*)&src[i];
        float4 b = *(const float4*)&src[i + 4];
        half8 h = {(_Float16)a.x, (_Float16)a.y, (_Float16)a.z, (_Float16)a.w,
                   (_Float16)b.x, (_Float16)b.y, (_Float16)b.z, (_Float16)b.w};
        *(half8*)&dst[i] = h;
    } else if (blk < 6160) {
        // ---- segment bounds ----
        int idx = (blk - 6144) * 256 + t;
        int b = idx / L, l = idx - b * L;
        const int* row = seq_id + (size_t)b * L;
        int v = row[l];
        int a = 0, c = L;
        while (a < c) { int m = (a + c) >> 1; if (row[m] < v) a = m + 1; else c = m; }
        lo[idx] = a;
        a = 0; c = L;
        while (a < c) { int m = (a + c) >> 1; if (row[m] <= v) a = m + 1; else c = m; }
        hi[idx] = a;
    } else {
        // ---- rope table: rtab[l*32+fi] = (cos, sin) of l * 10000^(-fi/32) ----
        int idx = (blk - 6160) * 256 + t;  // 0..65535
        int l = idx >> 5, fi = idx & 31;
        float invf = expf(-(float)fi * 0.28782313662425572f);  // ln(10000)/32
        float sn, cs;
        sincosf((float)l * invf, &sn, &cs);
        rtab[idx] = make_float2(cs, sn);
    }
}

// ---------------------------------------------------------------------------
// K2a: 256x256 8-phase COUNTED-VMCNT f16 GEMM for the QKV projection.
// C[4096,3072] = A[4096,1024] * W[3072,1024]^T, BK=64, 8 waves (2Mx4N),
// 128KB double-buffered LDS, 192 blocks (1/CU).
//
// The r2 port drained vmcnt(0) every K-tile (== 2-barrier perf, m218).
// This version keeps the drain COUNTED via region-death analysis:
//   - wave (wm,wn) reads ONLY A-half wm (rows wm*128..+127) and B-half wn>>1.
//   - buf p's A-half0 region is globally dead after ph2's barrier (last reads
//     ph0/ph2, each lgkmcnt-waited before that phase's MFMA, then barrier'd).
//   - stage placement:  A1(t+1)->p^1 @ph0(t)   [p^1's A1 dead since ph2(t-1)]
//                       B0(t+1)->p^1 @ph1(t)   [dead since ph1(t-1)]
//                       B1(t+1)->p^1 @ph2(t)   [dead since ph1(t-1)]
//                       A0(t+2)->p   @ph3(t)   [dead after ph2(t) barrier]
//   - once per tile, end of ph3: s_waitcnt vmcnt(2) — drains exactly the four
//     half-tiles of t+1 (issued >=1 full MFMA-phase earlier), leaves A0(t+2)
//     in flight. Every wave executes the same wait, so after the barrier all
//     waves' contributions to t+1's regions are complete. Tails: kt==14 ->
//     vmcnt(0) (no A0 stage issued), kt==15 -> none.
// T5: setprio(1) around each 16-MFMA cluster (m218b: +21-25% on 8-phase).
// XOR chunk swizzle via pre-swizzled global source (m173); reads XOR row&7.
// ---------------------------------------------------------------------------
#define LDA_HALF(BUF, MH, DST)                                                      \
    _Pragma("unroll") for (int mt = 0; mt < 4; mt++) {                              \
        int row_ = mw + (MH) * 64 + mt * 16 + col;                                  \
        _Pragma("unroll") for (int kk = 0; kk < 2; kk++)                            \
            DST[mt][kk] = *(const half8*)&As[BUF][row_][((kk * 4 + quad) ^ (row_ & 7)) * 8]; \
    }

#define LDB_HALF(BUF, NH, DST)                                                      \
    _Pragma("unroll") for (int nt = 0; nt < 2; nt++) {                              \
        int row_ = nw + (NH) * 32 + nt * 16 + col;                                  \
        _Pragma("unroll") for (int kk = 0; kk < 2; kk++)                            \
            DST[nt][kk] = *(const half8*)&Bs[BUF][row_][((kk * 4 + quad) ^ (row_ & 7)) * 8]; \
    }

#define MMA_QUAD(MH, NH, AF, BF)                                                    \
    __builtin_amdgcn_s_setprio(1);                                                  \
    _Pragma("unroll") for (int mt = 0; mt < 4; mt++)                                \
    _Pragma("unroll") for (int nt = 0; nt < 2; nt++) {                              \
        acc[(MH) * 4 + mt][(NH) * 2 + nt] = __builtin_amdgcn_mfma_f32_16x16x32_f16( \
            AF[mt][0], BF[nt][0], acc[(MH) * 4 + mt][(NH) * 2 + nt], 0, 0, 0);      \
        acc[(MH) * 4 + mt][(NH) * 2 + nt] = __builtin_amdgcn_mfma_f32_16x16x32_f16( \
            AF[mt][1], BF[nt][1], acc[(MH) * 4 + mt][(NH) * 2 + nt], 0, 0, 0);      \
    }                                                                               \
    __builtin_amdgcn_s_setprio(0);

__global__ __launch_bounds__(512, 2) void gemm1_8phase(const _Float16* __restrict__ A,
                                                       const _Float16* __restrict__ W,
                                                       _Float16* __restrict__ C,
                                                       _Float16* __restrict__ v_t) {
    __shared__ _Float16 As[2][256][64];
    __shared__ _Float16 Bs[2][256][64];
    int t = threadIdx.x;
    int w = t >> 6, lane = t & 63;
    int quad = lane >> 4, col = lane & 15;

    // XCD-aware 2D swizzle over the (12 N, 16 M) grid, 192 blocks, 192%8==0.
    int i = blockIdx.y * 12 + blockIdx.x;
    int xcd = i & 7, j = i >> 3;                 // j in [0,24)
    int tm = (xcd >> 1) * 4 + j / 6;             // [0,16)
    int tn = (xcd & 1) * 6 + j % 6;              // [0,12)
    int m0 = tm * 256, n0 = tn * 256;
    int mw = (w >> 2) * 128, nw = (w & 3) * 64;

    f32x4 acc[8][4] = {};

    // one half-tile = 128 rows x 64 k = 2 global_load_lds per thread
    auto stageA = [&](int kt, int buf, int half) {
#pragma unroll
        for (int ii = 0; ii < 2; ii++) {
            int e = half * 1024 + ii * 512 + t;
            int row = e >> 3, ch = e & 7;
            int sch = ch ^ (row & 7);
            __builtin_amdgcn_global_load_lds(
                (const __attribute__((address_space(1))) void*)&A[(size_t)(m0 + row) * 1024 + kt * 64 + sch * 8],
                (__attribute__((address_space(3))) void*)&As[buf][row][ch * 8], 16, 0, 0);
        }
    };
    auto stageB = [&](int kt, int buf, int half) {
#pragma unroll
        for (int ii = 0; ii < 2; ii++) {
            int e = half * 1024 + ii * 512 + t;
            int row = e >> 3, ch = e & 7;
            int sch = ch ^ (row & 7);
            __builtin_amdgcn_global_load_lds(
                (const __attribute__((address_space(1))) void*)&W[(size_t)(n0 + row) * 1024 + kt * 64 + sch * 8],
                (__attribute__((address_space(3))) void*)&Bs[buf][row][ch * 8], 16, 0, 0);
        }
    };

    // prologue: tile0 fully + A0(1); counted wait leaves A0(1) in flight
    stageA(0, 0, 0); stageA(0, 0, 1); stageB(0, 0, 0); stageB(0, 0, 1);
    stageA(1, 1, 0);
    asm volatile("s_waitcnt vmcnt(2)" ::: "memory");
    __builtin_amdgcn_s_barrier();

    half8 af[4][2], bf0[2][2], bf1[2][2];
    for (int kt = 0; kt < 16; kt++) {
        int p = kt & 1, np = p ^ 1;

        // ph0: quadrant (mh0, nh0) ; stage A1(t+1)
        LDA_HALF(p, 0, af);
        LDB_HALF(p, 0, bf0);
        if (kt + 1 < 16) stageA(kt + 1, np, 1);
        __builtin_amdgcn_s_barrier();
        MMA_QUAD(0, 0, af, bf0);
        __builtin_amdgcn_s_barrier();

        // ph1: quadrant (mh0, nh1) ; stage B0(t+1)
        LDB_HALF(p, 1, bf1);
        if (kt + 1 < 16) stageB(kt + 1, np, 0);
        __builtin_amdgcn_s_barrier();
        MMA_QUAD(0, 1, af, bf1);
        __builtin_amdgcn_s_barrier();

        // ph2: quadrant (mh1, nh1) ; stage B1(t+1)
        LDA_HALF(p, 1, af);
        if (kt + 1 < 16) stageB(kt + 1, np, 1);
        __builtin_amdgcn_s_barrier();
        MMA_QUAD(1, 1, af, bf1);
        __builtin_amdgcn_s_barrier();

        // ph3: quadrant (mh1, nh0) from regs ; stage A0(t+2) into buf p
        // (p's A-half0 is globally dead after ph2's barrier)
        if (kt + 2 < 16) stageA(kt + 2, p, 0);
        MMA_QUAD(1, 0, af, bf0);
        if (kt < 14)       { asm volatile("s_waitcnt vmcnt(2)" ::: "memory"); }
        else if (kt == 14) { asm volatile("s_waitcnt vmcnt(0)" ::: "memory"); }
        if (kt < 15) __builtin_amdgcn_s_barrier();
    }

    if (n0 >= 2048) {
        // pure-V block: write transposed v_t[bh][d][l] directly (VSPLIT)
        int b = m0 >> 11;
#pragma unroll
        for (int mt = 0; mt < 8; mt++)
#pragma unroll
            for (int nt = 0; nt < 4; nt++) {
                int vcol = n0 - 2048 + nw + nt * 16 + col;  // h*64 + d
                int bh = b * H + (vcol >> 6);
                int d = vcol & 63;
                int l = (m0 & (L - 1)) + mw + mt * 16 + quad * 4;
                half4v pk = {(_Float16)acc[mt][nt][0], (_Float16)acc[mt][nt][1],
                             (_Float16)acc[mt][nt][2], (_Float16)acc[mt][nt][3]};
                *(half4v*)&v_t[((size_t)(bh * 64 + d)) * 2048 + l] = pk;
            }
    } else {
#pragma unroll
        for (int mt = 0; mt < 8; mt++)
#pragma unroll
            for (int nt = 0; nt < 4; nt++)
#pragma unroll
                for (int r = 0; r < 4; r++) {
                    int row = m0 + mw + mt * 16 + quad * 4 + r;
                    int cc = n0 + nw + nt * 16 + col;
                    C[(size_t)row * 3072 + cc] = (_Float16)acc[mt][nt][r];
                }
    }
}

// ---------------------------------------------------------------------------
// K2b: f16 MFMA GEMM (out-proj). BM x BN tile, BK=32, 4 waves in 2x2.
// Single-barrier double-buffered K-loop; XOR source-swizzle; bijective
// linear XCD chunk swizzle (nwg % 8 == 0).
// ---------------------------------------------------------------------------
template <typename OutT, int BM, int BN>
__global__ __launch_bounds__(256) void gemm_f16_kernel(const _Float16* __restrict__ A,
                                                       const _Float16* __restrict__ W,
                                                       OutT* __restrict__ C, int N) {
    constexpr int WM = BM / 2, WN = BN / 2;
    constexpr int MT = WM / 16, NT = WN / 16;
    __shared__ _Float16 As[2][BM * 32];
    __shared__ _Float16 Bs[2][BN * 32];
    int t = threadIdx.x;
    int w = t >> 6, lane = t & 63;
    int quad = lane >> 4, col = lane & 15;
    int nx = gridDim.x;
    int ib = blockIdx.y * nx + blockIdx.x;
    int nwg = nx * gridDim.y;
    int ni = (ib & 7) * (nwg >> 3) + (ib >> 3);
    int m0 = (ni / nx) * BM, n0 = (ni % nx) * BN;
    int mw = (w >> 1) * WM, nw = (w & 1) * WN;
    int sw = (col >> 1) & 3;  // fragment-read swizzle == (row>>1)&3 for row=…+col

    f32x4 acc[MT][NT] = {};

    auto stage = [&](int k0, int buf) {
#pragma unroll
        for (int i = 0; i < BM / 64; i++) {
            int e = t + i * 256;
            int row = e >> 2, kc = (e & 3) ^ ((row >> 1) & 3);
            __builtin_amdgcn_global_load_lds(
                (const __attribute__((address_space(1))) void*)&A[(size_t)(m0 + row) * 1024 + k0 + kc * 8],
                (__attribute__((address_space(3))) void*)&As[buf][e * 8], 16, 0, 0);
        }
#pragma unroll
        for (int i = 0; i < BN / 64; i++) {
            int e = t + i * 256;
            int row = e >> 2, kc = (e & 3) ^ ((row >> 1) & 3);
            __builtin_amdgcn_global_load_lds(
                (const __attribute__((address_space(1))) void*)&W[(size_t)(n0 + row) * 1024 + k0 + kc * 8],
                (__attribute__((address_space(3))) void*)&Bs[buf][e * 8], 16, 0, 0);
        }
    };

    stage(0, 0);
    int cur = 0;
    for (int k0 = 0; k0 < 1024; k0 += 32) {
        __syncthreads();
        if (k0 + 32 < 1024) stage(k0 + 32, cur ^ 1);
        half8 af[MT], bf[NT];
#pragma unroll
        for (int mt = 0; mt < MT; mt++)
            af[mt] = *(const half8*)&As[cur][(mw + mt * 16 + col) * 32 + ((quad ^ sw) << 3)];
#pragma unroll
        for (int nt = 0; nt < NT; nt++)
            bf[nt] = *(const half8*)&Bs[cur][(nw + nt * 16 + col) * 32 + ((quad ^ sw) << 3)];
#pragma unroll
        for (int mt = 0; mt < MT; mt++)
#pragma unroll
            for (int nt = 0; nt < NT; nt++)
                acc[mt][nt] = __builtin_amdgcn_mfma_f32_16x16x32_f16(af[mt], bf[nt], acc[mt][nt], 0, 0, 0);
        cur ^= 1;
    }

#pragma unroll
    for (int mt = 0; mt < MT; mt++)
#pragma unroll
        for (int nt = 0; nt < NT; nt++)
#pragma unroll
            for (int r = 0; r < 4; r++) {
                int row = m0 + mw + mt * 16 + quad * 4 + r;
                int cc = n0 + nw + nt * 16 + col;
                C[(size_t)row * N + cc] = (OutT)acc[mt][nt][r];
            }
}

// ---------------------------------------------------------------------------
// K3: mid kernel — Q/K LayerNorm + RoPE -> f16 q_r/k_r, one block per row,
// 16B half8 loads/stores. Thread t<128 owns q elems 8t..8t+7; t>=128 same
// for k. RoPE partner j^32 == lane^4. (V handled by gemm1's VSPLIT epilogue.)
// ---------------------------------------------------------------------------
__global__ __launch_bounds__(256) void mid_kernel(const _Float16* __restrict__ qkv,
                                                  const float* __restrict__ qw,
                                                  const float* __restrict__ kw,
                                                  const float2* __restrict__ rtab,
                                                  _Float16* __restrict__ q_r,
                                                  _Float16* __restrict__ k_r) {
    __shared__ float ls[4], lq[4];
    int t = threadIdx.x;
    int r = blockIdx.x;
    int half = t >> 7;      // 0 = q, 1 = k (wave-uniform)
    int tt = t & 127;
    const _Float16* src = qkv + (size_t)r * 3072 + half * 1024;
    const float* wgt = half ? kw : qw;
    _Float16* dst = half ? k_r : q_r;

    half8 hv = *(const half8*)&src[tt * 8];
    float y[8];
    float s = 0.f, sq = 0.f;
#pragma unroll
    for (int e = 0; e < 8; e++) {
        float v = (float)hv[e];
        y[e] = v;
        s += v;
        sq += v * v;
    }
    for (int off = 32; off > 0; off >>= 1) {
        s += __shfl_xor(s, off, 64);
        sq += __shfl_xor(sq, off, 64);
    }
    int wave = t >> 6;
    if ((t & 63) == 0) { ls[wave] = s; lq[wave] = sq; }
    __syncthreads();
    int base = half << 1;
    float S = ls[base] + ls[base + 1];
    float Q = lq[base] + lq[base + 1];
    float mu = S / 1024.f;
    float rs = rsqrtf(Q / 1024.f - mu * mu + EPS);

    int l = r & (L - 1);
    int b = r >> 11;
    int j0 = tt * 8;
    int dh0 = j0 & 63, hh = j0 >> 6;
    const float2* cp = &rtab[l * 32 + (dh0 & 31)];
    float4 c01 = *(const float4*)cp;          // (cos,sin) pairs e=0,1
    float4 c23 = *(const float4*)(cp + 2);
    float4 c45 = *(const float4*)(cp + 4);
    float4 c67 = *(const float4*)(cp + 6);
    float cs_[8] = {c01.x, c01.z, c23.x, c23.z, c45.x, c45.z, c67.x, c67.z};
    float sn_[8] = {c01.y, c01.w, c23.y, c23.w, c45.y, c45.w, c67.y, c67.w};

    float yn[8];
#pragma unroll
    for (int e = 0; e < 8; e++) yn[e] = (y[e] - mu) * rs * wgt[j0 + e];
    float sgn = (dh0 < 32) ? -1.f : 1.f;
    half8 o;
#pragma unroll
    for (int e = 0; e < 8; e++) {
        float p = __shfl_xor(yn[e], 4, 64);   // partner element j^32
        o[e] = (_Float16)(yn[e] * cs_[e] + sgn * p * sn_[e]);
    }
    *(half8*)&dst[((size_t)((b * H + hh) * L + l)) * 64 + dh0] = o;
}

// ---------------------------------------------------------------------------
// K4: MFMA flash attention, segment-pruned, swapped-operand layout.
// QBLK=128 (8 waves), KV tile 64, double-buffered global_load_lds staging
// with pre-swizzled global source. mfma(K,Q) puts a full P-row in-lane
// (query = col); softmax = 15 in-lane ops + 2 shfl; P via 4 packed b64
// writes to XOR-swizzled wave-private Ps. LDS 48KB.
// ---------------------------------------------------------------------------
__global__ __launch_bounds__(512) void attn_mfma_kernel(const _Float16* __restrict__ q_r,
                                                        const _Float16* __restrict__ k_r,
                                                        const _Float16* __restrict__ v_t,
                                                        const int* __restrict__ lo_arr,
                                                        const int* __restrict__ hi_arr,
                                                        _Float16* __restrict__ ctx) {
    __shared__ _Float16 Ks[2][64][64];
    __shared__ _Float16 Vs[2][64][64];
    __shared__ _Float16 Ps[8][16][64];
    int bh = blockIdx.y;
    int b = bh >> 4, h = bh & 15;
    int l0 = blockIdx.x * 128;
    int t = threadIdx.x;
    int w = t >> 6, lane = t & 63;
    int quad = lane >> 4, col = lane & 15;
    int rbase = l0 + w * 16;

    int blo = lo_arr[b * L + l0] & ~63;
    int bhi = hi_arr[b * L + l0 + 127];

    auto stage = [&](int m0, int buf) {
        int row = t >> 3, ch = t & 7;          // 512 threads = 64 rows x 8 chunks
        int sch = ch ^ (row & 7);              // pre-swizzled global source (m173)
        __builtin_amdgcn_global_load_lds(
            (const __attribute__((address_space(1))) void*)&k_r[((size_t)(bh * L + m0 + row)) * 64 + sch * 8],
            (__attribute__((address_space(3))) void*)&Ks[buf][row][ch * 8], 16, 0, 0);
        __builtin_amdgcn_global_load_lds(
            (const __attribute__((address_space(1))) void*)&v_t[((size_t)(bh * 64 + row)) * 2048 + m0 + sch * 8],
            (__attribute__((address_space(3))) void*)&Vs[buf][row][ch * 8], 16, 0, 0);
    };

    stage(blo, 0);

    // Q fragment (B-operand): B[col=query][k = quad*8..], query = rbase+col
    half8 qf0, qf1;
    {
        const _Float16* qp = q_r + ((size_t)(bh * L + rbase + col)) * 64 + quad * 8;
        qf0 = *(const half8*)qp;
        qf1 = *(const half8*)(qp + 32);
    }
    int lo_c = lo_arr[b * L + rbase + col];  // per-lane query bounds
    int hi_c = hi_arr[b * L + rbase + col];
    int wlo = __shfl(lo_c, 15, 64);  // max lo over wave's queries (monotone)
    int whi = __shfl(hi_c, 0, 64);   // min hi over wave's queries

    f32x4 o[4] = {};
    float m_run = -1e30f, l_run = 0.f;
    const float SCL = 0.125f * 1.4426950408889634f;  // (1/sqrt(DH)) * log2(e)
    int swz = (col & 7) << 3;
    int src = (lane & 48) | ((lane & 48) >> 2);  // lane holding corr for row quad*4+r

    int cur = 0;
    for (int m0 = blo; m0 < bhi; m0 += 64) {
        __syncthreads();  // implicit vmcnt(0): buf[cur] staged by all waves
        if (m0 + 64 < bhi) stage(m0 + 64, cur ^ 1);

        // QK^T swapped: s[nt] row = key (nt*16 + quad*4 + r), col = query
        f32x4 s[4] = {};
#pragma unroll
        for (int nt = 0; nt < 4; nt++) {
            int key = nt * 16 + col;
            const _Float16* kp = &Ks[cur][key][0];
            half8 kf0 = *(const half8*)&kp[(quad ^ (key & 7)) * 8];
            half8 kf1 = *(const half8*)&kp[((quad + 4) ^ (key & 7)) * 8];
            s[nt] = __builtin_amdgcn_mfma_f32_16x16x32_f16(kf0, qf0, s[nt], 0, 0, 0);
            s[nt] = __builtin_amdgcn_mfma_f32_16x16x32_f16(kf1, qf1, s[nt], 0, 0, 0);
        }

        float p[4][4];
        bool full = (m0 >= wlo) && (m0 + 64 <= whi);  // wave-uniform branch
        if (full) {
#pragma unroll
            for (int nt = 0; nt < 4; nt++)
#pragma unroll
                for (int r = 0; r < 4; r++) p[nt][r] = s[nt][r] * SCL;
        } else {
#pragma unroll
            for (int nt = 0; nt < 4; nt++) {
                int kb = m0 + nt * 16 + quad * 4;
#pragma unroll
                for (int r = 0; r < 4; r++) {
                    int key = kb + r;
                    p[nt][r] = (key >= lo_c && key < hi_c) ? s[nt][r] * SCL : -INFINITY;
                }
            }
        }

        // online softmax for this lane's query (col): 15 in-lane + 2 shfl
        float tmax = p[0][0];
#pragma unroll
        for (int nt = 0; nt < 4; nt++)
#pragma unroll
            for (int r = 0; r < 4; r++) tmax = fmaxf(tmax, p[nt][r]);
        tmax = fmaxf(tmax, __shfl_xor(tmax, 16, 64));
        tmax = fmaxf(tmax, __shfl_xor(tmax, 32, 64));
        float nm = fmaxf(m_run, tmax);
        float corr = exp2f(m_run - nm);
        m_run = nm;
        float rs = 0.f;
#pragma unroll
        for (int nt = 0; nt < 4; nt++)
#pragma unroll
            for (int r = 0; r < 4; r++) {
                float e2 = exp2f(p[nt][r] - nm);
                p[nt][r] = e2;
                rs += e2;
            }
        rs += __shfl_xor(rs, 16, 64);
        rs += __shfl_xor(rs, 32, 64);
        l_run = l_run * corr + rs;

        // P -> LDS: 4 packed b64 writes, Ps[w][query][key ^ swz(query)]
#pragma unroll
        for (int nt = 0; nt < 4; nt++) {
            half4v pk = {(_Float16)p[nt][0], (_Float16)p[nt][1],
                         (_Float16)p[nt][2], (_Float16)p[nt][3]};
            *(half4v*)&Ps[w][col][(nt * 16 + quad * 4) ^ swz] = pk;
        }

        // O-rescale: corr lives at lanes with col==query; PV rows are quad*4+r
#pragma unroll
        for (int r = 0; r < 4; r++) {
            float c4 = __shfl(corr, src + r, 64);
            o[0][r] *= c4; o[1][r] *= c4; o[2][r] *= c4; o[3][r] *= c4;
        }

        // PV: A = P[query][key], B = V^T[d][key]
        half8 pf0 = *(const half8*)&Ps[w][col][(quad * 8) ^ swz];
        half8 pf1 = *(const half8*)&Ps[w][col][(32 + quad * 8) ^ swz];
#pragma unroll
        for (int nt = 0; nt < 4; nt++) {
            int dr = nt * 16 + col;
            const _Float16* vp = &Vs[cur][dr][0];
            half8 vf0 = *(const half8*)&vp[(quad ^ (dr & 7)) * 8];
            half8 vf1 = *(const half8*)&vp[((quad + 4) ^ (dr & 7)) * 8];
            o[nt] = __builtin_amdgcn_mfma_f32_16x16x32_f16(pf0, vf0, o[nt], 0, 0, 0);
            o[nt] = __builtin_amdgcn_mfma_f32_16x16x32_f16(pf1, vf1, o[nt], 0, 0, 0);
        }
        cur ^= 1;
    }

#pragma unroll
    for (int r = 0; r < 4; r++) {
        float linv = 1.f / __shfl(l_run, src + r, 64);
        int row = rbase + quad * 4 + r;
#pragma unroll
        for (int nt = 0; nt < 4; nt++)
            ctx[((size_t)(b * L + row)) * 1024 + h * 64 + nt * 16 + col] =
                (_Float16)(o[nt][r] * linv);
    }
}

// ---------------------------------------------------------------------------
// launch
// ---------------------------------------------------------------------------
extern "C" void kernel_launch(void* const* d_in, const int* in_sizes, int n_in,
                              void* d_out, int out_size, void* d_ws, size_t ws_size,
                              hipStream_t stream) {
    const float* x      = (const float*)d_in[0];
    const int*   seq_id = (const int*)d_in[1];
    const float* ln1_w  = (const float*)d_in[2];
    const float* ln1_b  = (const float*)d_in[3];
    const float* w_qkv  = (const float*)d_in[4];
    const float* q_ln_w = (const float*)d_in[5];
    const float* k_ln_w = (const float*)d_in[6];
    const float* out_w  = (const float*)d_in[7];
    float* out = (float*)d_out;

    char* ws = (char*)d_ws;
    int*      lo     = (int*)(ws);                        // 16 KB
    int*      hi     = (int*)(ws + (64 << 10));           // 16 KB
    float2*   rtab   = (float2*)(ws + (128 << 10));       // [2048][32] f32x2, 512 KB
    _Float16* h16    = (_Float16*)(ws + (1ull << 20));    // [4096,1024] 8 MB
    _Float16* wqkv16 = (_Float16*)(ws + (10ull << 20));   // [3072,1024] 6 MB
    _Float16* outw16 = (_Float16*)(ws + (17ull << 20));   // [1024,1024] 2 MB
    _Float16* qkv16  = (_Float16*)(ws + (20ull << 20));   // [4096,3072] 24 MB (V third unused)
    _Float16* q_r    = (_Float16*)(ws + (45ull << 20));   // [B,H,L,DH] 8 MB
    _Float16* k_r    = (_Float16*)(ws + (54ull << 20));   // 8 MB
    _Float16* v_t    = (_Float16*)(ws + (63ull << 20));   // [B,H,DH,L] 8 MB
    _Float16* ctx16  = (_Float16*)(ws + (72ull << 20));   // [4096,1024] 8 MB

    prep_kernel<<<dim3(6416), dim3(256), 0, stream>>>(
        x, ln1_w, ln1_b, h16, w_qkv, wqkv16, out_w, outw16, seq_id, lo, hi, rtab);
    gemm1_8phase<<<dim3(12, 16), dim3(512), 0, stream>>>(h16, wqkv16, qkv16, v_t);
    mid_kernel<<<dim3(4096), dim3(256), 0, stream>>>(qkv16, q_ln_w, k_ln_w, rtab, q_r, k_r);
    attn_mfma_kernel<<<dim3(L / 128, B * H), dim3(512), 0, stream>>>(q_r, k_r, v_t, lo, hi, ctx16);
    gemm_f16_kernel<float, 128, 64><<<dim3(1024 / 64, NROW / 128), dim3(256), 0, stream>>>(
        ctx16, outw16, out, 1024);

    (void)in_sizes; (void)n_in; (void)out_size; (void)ws_size;
}